// Round 16
// baseline (648.039 us; speedup 1.0000x reference)
//
#include <hip/hip_runtime.h>
#include <hip/hip_bf16.h>
#include <hip/hip_fp16.h>

#define DI __device__ __forceinline__

typedef short bf16x8 __attribute__((ext_vector_type(8)));
typedef float f32x4 __attribute__((ext_vector_type(4)));
using bf16 = __hip_bfloat16;

typedef __attribute__((address_space(3))) void lds_void;
typedef const __attribute__((address_space(1))) void glob_void;

constexpr int Tn = 16384, Sn = 256, En = 1024;
constexpr float SCALEF = 0.08838834764831845f;   // 128^-0.5
constexpr float CLAMPF = 50000.0f;

DI f32x4 mfma16(bf16x8 a, bf16x8 b, f32x4 c) {
  return __builtin_amdgcn_mfma_f32_16x16x32_bf16(a, b, c, 0, 0, 0);
}
DI unsigned short f2bu(float x) { bf16 h = __float2bfloat16(x); return *(unsigned short*)&h; }
DI unsigned int pack2(float lo, float hi) { return (unsigned)f2bu(lo) | ((unsigned)f2bu(hi) << 16); }
DI bf16x8 ldg8(const bf16* p) { return *(const bf16x8*)p; }
DI float clampf(float v) { return fminf(fmaxf(v, -CLAMPF), CLAMPF); }
DI unsigned int packh2(float a, float b) {
  __half2 h = __floats2half2_rn(a, b);
  return *(unsigned int*)&h;
}
DI void gload16(const bf16* g, bf16* lds_base) {
  __builtin_amdgcn_global_load_lds((glob_void*)g, (lds_void*)lds_base, 16, 0, 0);
}

// ---------------- f32 -> bf16 bulk cast (vectorized x4) ----------------
__global__ void cast_f32_bf16_v4(const float* __restrict__ in, bf16* __restrict__ out, int n4) {
  int i = blockIdx.x * 256 + threadIdx.x;
  if (i >= n4) return;
  float4 f = reinterpret_cast<const float4*>(in)[i];
  unsigned long long u = (unsigned long long)pack2(f.x, f.y) |
                         ((unsigned long long)pack2(f.z, f.w) << 32);
  *reinterpret_cast<unsigned long long*>(out + (size_t)i * 4) = u;
}

// ---------------- weight transpose+cast W[K][N] -> Wt[N][K], y=0..5 ----------------
__global__ void cast_weights(const float* __restrict__ w0, bf16* __restrict__ o0,
                             const float* __restrict__ w1, bf16* __restrict__ o1,
                             const float* __restrict__ w2, bf16* __restrict__ o2,
                             const float* __restrict__ w3, bf16* __restrict__ o3,
                             const float* __restrict__ w4, bf16* __restrict__ o4,
                             const float* __restrict__ w5, bf16* __restrict__ o5) {
  int id = blockIdx.x * 256 + threadIdx.x;
  switch (blockIdx.y) {
    case 0: if (id < 256*1024) { int k = id >> 10, n = id & 1023; o0[n*256 + k] = __float2bfloat16(w0[id]); } break;
    case 1: if (id < 256*1024) { int k = id >> 10, n = id & 1023; o1[n*256 + k] = __float2bfloat16(w1[id]); } break;
    case 2: if (id < 768*1024) { int k = id >> 10, n = id & 1023; o2[n*768 + k] = __float2bfloat16(w2[id]); } break;
    case 3: if (id < 768*1024) { int k = id >> 10, n = id & 1023; o3[n*768 + k] = __float2bfloat16(w3[id]); } break;
    case 4: if (id < 1024*256) { int k = id >> 8,  n = id & 255;  o4[n*1024 + k] = __float2bfloat16(w4[id]); } break;
    case 5: if (id < 1024*768) { int k = id / 768, n = id % 768;  o5[n*1024 + k] = __float2bfloat16(w5[id]); } break;
  }
}

// ---------------- generic 128x128 MFMA GEMM (R12-proven) ----------------
template<int MODE>
__global__ __launch_bounds__(256) void gemm_kern(
    const bf16* __restrict__ A, const bf16* __restrict__ Bw0, const bf16* __restrict__ Bw1,
    const float* __restrict__ bias0, const float* __restrict__ bias1,
    void* __restrict__ out0, void* __restrict__ out1, int zbase)
{
  constexpr int K = (MODE == 0) ? 256 : (MODE == 1) ? 768 : 1024;
  const int z = blockIdx.z + zbase;
  const bf16* Bw = z ? Bw1 : Bw0;
  const float* bias = z ? bias1 : bias0;
  const int m0 = blockIdx.x * 128, n0 = blockIdx.y * 128;
  const int tid = threadIdx.x, lane = tid & 63;
  const int w = tid >> 6, wm = w >> 1, wn = w & 1;
  const int l15 = lane & 15, l4 = lane >> 4;

  __shared__ bf16 smem[128 * 136];
  bf16* As = smem;
  bf16* Bs = smem + 128 * 64;

  const int lr = lane >> 3, lp = lane & 7;

  f32x4 acc[4][4];
  #pragma unroll
  for (int a = 0; a < 4; a++)
    #pragma unroll
    for (int c = 0; c < 4; c++) acc[a][c] = f32x4{0.f, 0.f, 0.f, 0.f};

  for (int k0 = 0; k0 < K; k0 += 64) {
    __syncthreads();
    #pragma unroll
    for (int it = 0; it < 4; it++) {
      const int row = it * 32 + w * 8 + lr;
      const int gc = lp ^ (row & 7);
      gload16(Bw + (size_t)(n0 + row) * K + k0 + gc * 8, Bs + (it * 32 + w * 8) * 64);
      gload16(A  + (size_t)(m0 + row) * K + k0 + gc * 8, As + (it * 32 + w * 8) * 64);
    }
    __syncthreads();
    #pragma unroll
    for (int ks = 0; ks < 2; ks++) {
      bf16x8 af[4], bfr[4];
      #pragma unroll
      for (int mf = 0; mf < 4; mf++) {
        int r = wm * 64 + mf * 16 + l15;
        af[mf] = *(const bf16x8*)(As + r * 64 + (((ks * 4 + l4) ^ (r & 7)) * 8));
      }
      #pragma unroll
      for (int nf = 0; nf < 4; nf++) {
        int r = wn * 64 + nf * 16 + l15;
        bfr[nf] = *(const bf16x8*)(Bs + r * 64 + (((ks * 4 + l4) ^ (r & 7)) * 8));
      }
      #pragma unroll
      for (int mf = 0; mf < 4; mf++)
        #pragma unroll
        for (int nf = 0; nf < 4; nf++)
          acc[mf][nf] = mfma16(af[mf], bfr[nf], acc[mf][nf]);
    }
  }
  __syncthreads();

  if constexpr (MODE <= 1) {
    #pragma unroll
    for (int nf = 0; nf < 4; nf++) {
      int nl = wn * 64 + nf * 16 + l15;
      float bv = bias[n0 + nl];
      #pragma unroll
      for (int mf = 0; mf < 4; mf++) {
        int ml = wm * 64 + mf * 16 + l4 * 4;
        #pragma unroll
        for (int i = 0; i < 4; i++) {
          float vv = acc[mf][nf][i] + bv;
          if (MODE == 0 && z == 0) vv *= SCALEF;
          smem[(ml + i) * 136 + nl] = __float2bfloat16(vv);
        }
      }
    }
    __syncthreads();
    constexpr int TT = (MODE == 0) ? Tn : Sn;
    const int h = n0 >> 7;
    const int r2 = tid >> 1, c0 = (tid & 1) * 64;
    if (z == 0) {
      int m = m0 + r2;
      int bq = (MODE == 0) ? 0 : (m >> 8);
      int t  = m & (TT - 1);
      bf16* out = (bf16*)out0;
      size_t base = ((size_t)(bq * 8 + h) * TT + t) * 128 + c0;
      #pragma unroll
      for (int j = 0; j < 32; j++) {
        unsigned int u = *(const unsigned int*)(smem + r2 * 136 + c0 + 2 * j);
        *(unsigned int*)(out + base + 2 * j) = u;
      }
    } else {
      int bq = (MODE == 0) ? 0 : (m0 >> 8);
      int t0 = m0 & (TT - 1);
      bf16* out = (bf16*)out1;
      size_t base = ((size_t)(bq * 8 + h) * 128 + r2) * TT + t0 + c0;
      #pragma unroll
      for (int j = 0; j < 32; j++) {
        unsigned short u0 = *(const unsigned short*)(smem + (c0 + 2 * j)     * 136 + r2);
        unsigned short u1 = *(const unsigned short*)(smem + (c0 + 2 * j + 1) * 136 + r2);
        *(unsigned int*)(out + base + 2 * j) = (unsigned)u0 | ((unsigned)u1 << 16);
      }
    }
  } else {
    constexpr int NOUT = (MODE == 2) ? 256 : 768;
    float* out = (float*)out0;
    #pragma unroll
    for (int nf = 0; nf < 4; nf++) {
      int n = n0 + wn * 64 + nf * 16 + l15;
      float bv = bias[n];
      #pragma unroll
      for (int mf = 0; mf < 4; mf++) {
        size_t mbase = (size_t)(m0 + wm * 64 + mf * 16 + l4 * 4) * NOUT + n;
        #pragma unroll
        for (int i = 0; i < 4; i++)
          out[mbase + (size_t)i * NOUT] = acc[mf][nf][i] + bv;
      }
    }
  }
}

// ---------------- FUSED attention v2.4: colPV hoisted before the mid barrier ---------
// Identical to R12/R15 v2.1 except tile-body order: colPV (which depends only on
// own-wave Etr + stable Vb[cur]) now executes BEFORE the mid barrier, overlapping the
// Enat/red LDS-write drain and shortening the post-barrier chain to rowsum+rowPV.
// Hazards re-audited: Etr RAW same-wave (lgkm order); Vb[cur] read vs Vb[cur^1]
// prefetch-write are disjoint halves; Enat/red write->read still cross the mid
// barrier; all WARs still cross the end barrier.
template<int NCH, bool SLAB>
__global__ __launch_bounds__(512, 2) void attn_fused(
    const bf16* __restrict__ qh,      // [8][Tn][128]
    const bf16* __restrict__ kh,      // [8][Sn][128]
    const bf16* __restrict__ vallT,   // [8][128][Sn]
    const bf16* __restrict__ valvT,   // [8][128][Tn]
    bf16* __restrict__ ovh,           // [Tn][En]
    void* __restrict__ col_dst,       // SLAB ? __half slab : float olh (pre-zeroed)
    float* __restrict__ dsum_dst)     // SLAB ? csum_slab : dsum (pre-zeroed, atomic)
{
  constexpr int SPAN = Tn / NCH;      // 512
  constexpr int TILES = SPAN / 64;    // 8
  const int ch = blockIdx.x, h = blockIdx.y;
  const int tid = threadIdx.x, lane = tid & 63, w = tid >> 6;   // 8 waves
  const int l15 = lane & 15, l4 = lane >> 4;
  const int sw = w * 32;
  const int e7 = l15 & 7;

  __shared__ bf16 Qb[2][64 * 128];    // 32 KB
  __shared__ bf16 Vb[2][128 * 64];    // 32 KB
  __shared__ bf16 Enat[64 * 264];     // 33.8 KB
  __shared__ bf16 Etr[8][32 * 72];    // 36.9 KB
  __shared__ float red[8][64];        // 2 KB   (total ~135 KB -> 1 blk/CU)

  const bf16* qp  = qh    + (size_t)h * Tn * 128;
  const bf16* kp  = kh    + (size_t)h * Sn * 128;
  const bf16* vlp = vallT + (size_t)h * 128 * Sn;
  const bf16* vvp = valvT + (size_t)h * 128 * Tn;
  const int tb0 = ch * SPAN;

  bf16x8 bkr[4][2];
  #pragma unroll
  for (int ks = 0; ks < 4; ks++)
    #pragma unroll
    for (int si = 0; si < 2; si++)
      bkr[ks][si] = ldg8(kp + (size_t)(sw + si * 16 + l15) * 128 + ks * 32 + l4 * 8);
  bf16x8 bvr[8];
  #pragma unroll
  for (int ks2 = 0; ks2 < 8; ks2++)
    bvr[ks2] = ldg8(vlp + (size_t)(w * 16 + l15) * Sn + ks2 * 32 + l4 * 8);

  const int q_r0 = tid >> 4, q_c = tid & 15;          // Q: 64r x 16c
  const int q_r1 = q_r0 + 32;
  const int v_r0 = tid >> 3, v_c = tid & 7;           // V: 128r x 8c
  const int v_r1 = v_r0 + 64;

  {
    uint4 q0 = *(const uint4*)(qp + (size_t)(tb0 + q_r0) * 128 + q_c * 8);
    uint4 q1 = *(const uint4*)(qp + (size_t)(tb0 + q_r1) * 128 + q_c * 8);
    uint4 v0 = *(const uint4*)(vvp + (size_t)v_r0 * Tn + tb0 + v_c * 8);
    uint4 v1 = *(const uint4*)(vvp + (size_t)v_r1 * Tn + tb0 + v_c * 8);
    *(uint4*)(&Qb[0][q_r0 * 128 + ((q_c ^ (q_r0 & 7)) * 8)]) = q0;
    *(uint4*)(&Qb[0][q_r1 * 128 + ((q_c ^ (q_r1 & 7)) * 8)]) = q1;
    *(uint4*)(&Vb[0][v_r0 * 64  + ((v_c ^ (v_r0 & 7)) * 8)]) = v0;
    *(uint4*)(&Vb[0][v_r1 * 64  + ((v_c ^ (v_r1 & 7)) * 8)]) = v1;
  }
  __syncthreads();

  f32x4 oc[8][2];
  #pragma unroll
  for (int a = 0; a < 8; a++)
    #pragma unroll
    for (int c = 0; c < 2; c++) oc[a][c] = f32x4{0.f, 0.f, 0.f, 0.f};
  float csum[2] = {0.f, 0.f};

  int cur = 0;
  for (int tt = 0; tt < TILES; tt++) {
    const int tb = tb0 + tt * 64;
    const bool hn = (tt + 1 < TILES);
    uint4 pfq0, pfq1, pfv0, pfv1;
    if (hn) {
      const int tbn = tb + 64;
      pfq0 = *(const uint4*)(qp + (size_t)(tbn + q_r0) * 128 + q_c * 8);
      pfq1 = *(const uint4*)(qp + (size_t)(tbn + q_r1) * 128 + q_c * 8);
      pfv0 = *(const uint4*)(vvp + (size_t)v_r0 * Tn + tbn + v_c * 8);
      pfv1 = *(const uint4*)(vvp + (size_t)v_r1 * Tn + tbn + v_c * 8);
    }
    // ---- QK^T from Qb[cur] ----
    f32x4 sacc[4][2];
    #pragma unroll
    for (int a = 0; a < 4; a++)
      #pragma unroll
      for (int c = 0; c < 2; c++) sacc[a][c] = f32x4{0.f, 0.f, 0.f, 0.f};
    #pragma unroll
    for (int ks = 0; ks < 4; ks++) {
      const int x = (ks * 4 + l4) ^ e7;
      bf16x8 aq[4];
      #pragma unroll
      for (int ti = 0; ti < 4; ti++)
        aq[ti] = *(const bf16x8*)(&Qb[cur][(ti * 16 + l15) * 128 + x * 8]);
      #pragma unroll
      for (int ti = 0; ti < 4; ti++)
        #pragma unroll
        for (int si = 0; si < 2; si++)
          sacc[ti][si] = mfma16(aq[ti], bkr[ks][si], sacc[ti][si]);
    }
    // ---- E = exp(clamp(S)) -> Enat + Etr; col sums; row partials ----
    float rp[4][4];
    #pragma unroll
    for (int ti = 0; ti < 4; ti++)
      #pragma unroll
      for (int i = 0; i < 4; i++) rp[ti][i] = 0.f;
    #pragma unroll
    for (int ti = 0; ti < 4; ti++)
      #pragma unroll
      for (int si = 0; si < 2; si++) {
        float e0 = __expf(clampf(sacc[ti][si][0]));
        float e1 = __expf(clampf(sacc[ti][si][1]));
        float e2 = __expf(clampf(sacc[ti][si][2]));
        float e3 = __expf(clampf(sacc[ti][si][3]));
        csum[si] += (e0 + e1) + (e2 + e3);
        rp[ti][0] += e0; rp[ti][1] += e1; rp[ti][2] += e2; rp[ti][3] += e3;
        unsigned long long u = (unsigned long long)pack2(e0, e1) |
                               ((unsigned long long)pack2(e2, e3) << 32);
        *(unsigned long long*)(&Etr[w][(si * 16 + l15) * 72 + ti * 16 + l4 * 4]) = u;
        const int s = sw + si * 16 + l15;
        const int t0 = ti * 16 + l4 * 4;
        Enat[(t0 + 0) * 264 + s] = __float2bfloat16(e0);
        Enat[(t0 + 1) * 264 + s] = __float2bfloat16(e1);
        Enat[(t0 + 2) * 264 + s] = __float2bfloat16(e2);
        Enat[(t0 + 3) * 264 + s] = __float2bfloat16(e3);
      }
    #pragma unroll
    for (int ti = 0; ti < 4; ti++)
      #pragma unroll
      for (int i = 0; i < 4; i++) {
        float r = rp[ti][i];
        #pragma unroll
        for (int off = 1; off < 16; off <<= 1) r += __shfl_xor(r, off);
        if (l15 == 0) red[w][ti * 16 + l4 * 4 + i] = r;
      }
    // ---- col-PV HOISTED: own-wave Etr + stable Vb[cur]; overlaps LDS-write drain ----
    #pragma unroll
    for (int kst = 0; kst < 2; kst++) {
      bf16x8 bp[2];
      #pragma unroll
      for (int si = 0; si < 2; si++)
        bp[si] = *(const bf16x8*)(&Etr[w][(si * 16 + l15) * 72 + kst * 32 + l4 * 8]);
      const int x = (kst * 4 + l4) ^ e7;
      #pragma unroll
      for (int mf = 0; mf < 8; mf++) {
        bf16x8 av = *(const bf16x8*)(&Vb[cur][(mf * 16 + l15) * 64 + x * 8]);
        #pragma unroll
        for (int si = 0; si < 2; si++)
          oc[mf][si] = mfma16(av, bp[si], oc[mf][si]);
      }
    }
    __syncthreads();                              // mid barrier
    float rsm[4][4];
    #pragma unroll
    for (int ti = 0; ti < 4; ti++)
      #pragma unroll
      for (int i = 0; i < 4; i++) {
        const int tl = ti * 16 + l4 * 4 + i;
        float s = red[0][tl] + red[1][tl] + red[2][tl] + red[3][tl] +
                  red[4][tl] + red[5][tl] + red[6][tl] + red[7][tl];
        rsm[ti][i] = 1.0f / s;
      }
    // ---- row-PV from Enat + hoisted bvr; in-kernel 1/rowsum scaling ----
    f32x4 orr[4];
    #pragma unroll
    for (int a = 0; a < 4; a++) orr[a] = f32x4{0.f, 0.f, 0.f, 0.f};
    #pragma unroll
    for (int ks2 = 0; ks2 < 8; ks2++) {
      const int soff = ks2 * 32 + l4 * 8;
      #pragma unroll
      for (int ti = 0; ti < 4; ti++) {
        bf16x8 ap = *(const bf16x8*)(Enat + (ti * 16 + l15) * 264 + soff);
        orr[ti] = mfma16(ap, bvr[ks2], orr[ti]);
      }
    }
    #pragma unroll
    for (int ti = 0; ti < 4; ti++) {
      size_t base = (size_t)(tb + ti * 16 + l4 * 4) * En + h * 128 + w * 16 + l15;
      #pragma unroll
      for (int i = 0; i < 4; i++)
        ovh[base + (size_t)i * En] = __float2bfloat16(orr[ti][i] * rsm[ti][i]);
    }
    // ---- write prefetched Q/V to the other buffer ----
    if (hn) {
      *(uint4*)(&Qb[cur ^ 1][q_r0 * 128 + ((q_c ^ (q_r0 & 7)) * 8)]) = pfq0;
      *(uint4*)(&Qb[cur ^ 1][q_r1 * 128 + ((q_c ^ (q_r1 & 7)) * 8)]) = pfq1;
      *(uint4*)(&Vb[cur ^ 1][v_r0 * 64  + ((v_c ^ (v_r0 & 7)) * 8)]) = pfv0;
      *(uint4*)(&Vb[cur ^ 1][v_r1 * 64  + ((v_c ^ (v_r1 & 7)) * 8)]) = pfv1;
    }
    __syncthreads();                              // end barrier
    cur ^= 1;
  }
  // ---- epilogue: col denominator + numerator ----
  #pragma unroll
  for (int si = 0; si < 2; si++) {
    float c = csum[si];
    c += __shfl_xor(c, 16);
    c += __shfl_xor(c, 32);
    if (l4 == 0) {
      if constexpr (SLAB) dsum_dst[((size_t)(ch * 8 + h)) * 256 + sw + si * 16 + l15] = c;
      else atomicAdd(&dsum_dst[h * 256 + sw + si * 16 + l15], c);
    }
  }
  if constexpr (SLAB) {
    __half* slab = (__half*)col_dst + ((size_t)(ch * 8 + h) * 256) * 128;
    #pragma unroll
    for (int mf = 0; mf < 8; mf++)
      #pragma unroll
      for (int si = 0; si < 2; si++) {
        const int s = sw + si * 16 + l15;
        const int d = mf * 16 + l4 * 4;
        uint2 u;
        u.x = packh2(oc[mf][si][0], oc[mf][si][1]);
        u.y = packh2(oc[mf][si][2], oc[mf][si][3]);
        *(uint2*)(slab + (size_t)s * 128 + d) = u;
      }
  } else {
    float* olh = (float*)col_dst;
    #pragma unroll
    for (int mf = 0; mf < 8; mf++)
      #pragma unroll
      for (int si = 0; si < 2; si++) {
        const int s = sw + si * 16 + l15;
        const int d = mf * 16 + l4 * 4;
        float* dst = olh + (size_t)s * 1024 + h * 128 + d;
        #pragma unroll
        for (int i = 0; i < 4; i++) atomicAdd(dst + i, oc[mf][si][i]);
      }
  }
}

// ---------------- slab reduce (fp16 numerator + f32 denominator) -> bf16 olhb --------
template<int NCH>
__global__ __launch_bounds__(256) void reduce_olh(
    const __half* __restrict__ slab, const float* __restrict__ csum_slab, bf16* __restrict__ olhb)
{
  int id = blockIdx.x * 256 + threadIdx.x;
  int s = id >> 8, hd4 = id & 255, h = hd4 >> 5, d4 = hd4 & 31;
  float a0 = 0.f, a1 = 0.f, a2 = 0.f, a3 = 0.f, dsv = 0.f;
  #pragma unroll 4
  for (int ch = 0; ch < NCH; ch++) {
    uint2 u = *(const uint2*)(slab + ((size_t)(ch * 8 + h) * 256 + s) * 128 + d4 * 4);
    __half2 x = *(__half2*)&u.x, y = *(__half2*)&u.y;
    a0 += __low2float(x); a1 += __high2float(x);
    a2 += __low2float(y); a3 += __high2float(y);
    dsv += csum_slab[((size_t)(ch * 8 + h)) * 256 + s];
  }
  float inv = 1.0f / dsv;
  unsigned long long u = (unsigned long long)pack2(a0 * inv, a1 * inv) |
                         ((unsigned long long)pack2(a2 * inv, a3 * inv) << 32);
  *reinterpret_cast<unsigned long long*>(olhb + (size_t)s * 1024 + h * 128 + d4 * 4) = u;
}

// ---------------- fallback normalize olh -> bf16 (per-b) ----------------
__global__ __launch_bounds__(256) void norm_olh(
    const float* __restrict__ olh, const float* __restrict__ dsum, bf16* __restrict__ olhb)
{
  int i = blockIdx.x * 256 + threadIdx.x;
  int s = i >> 8, c4 = i & 255;
  float inv = 1.0f / dsum[(c4 >> 5) * 256 + s];
  float4 x = reinterpret_cast<const float4*>(olh + (size_t)s * 1024)[c4];
  unsigned long long u = (unsigned long long)pack2(x.x * inv, x.y * inv) |
                         ((unsigned long long)pack2(x.z * inv, x.w * inv) << 32);
  *reinterpret_cast<unsigned long long*>(olhb + (size_t)s * 1024 + c4 * 4) = u;
}

// ---------------- launch ----------------
extern "C" void kernel_launch(void* const* d_in, const int* in_sizes, int n_in,
                              void* d_out, int out_size, void* d_ws, size_t ws_size,
                              hipStream_t stream)
{
  (void)in_sizes; (void)n_in;
  const float* v        = (const float*)d_in[0];
  const float* l        = (const float*)d_in[1];
  const float* v_proj_w = (const float*)d_in[2];
  const float* v_proj_b = (const float*)d_in[3];
  const float* l_proj_w = (const float*)d_in[4];
  const float* l_proj_b = (const float*)d_in[5];
  const float* vv_w     = (const float*)d_in[6];
  const float* vv_b     = (const float*)d_in[7];
  const float* vl_w     = (const float*)d_in[8];
  const float* vl_b     = (const float*)d_in[9];
  const float* ov_w     = (const float*)d_in[10];
  const float* ov_b     = (const float*)d_in[11];
  const float* ol_w     = (const float*)d_in[12];
  const float* ol_b     = (const float*)d_in[13];

  char* ws = (char*)d_ws;
  size_t off = 0;
  auto alloc = [&](size_t bytes) -> char* {
    char* p = ws + off;
    off += (bytes + 255) & ~(size_t)255;
    return p;
  };

  // persistent (~18 MB)
  bf16*  wqt   = (bf16*)alloc((size_t)1024 * 256 * 2);
  bf16*  wvvt  = (bf16*)alloc((size_t)1024 * 256 * 2);
  bf16*  wkt   = (bf16*)alloc((size_t)1024 * 768 * 2);
  bf16*  wvlt  = (bf16*)alloc((size_t)1024 * 768 * 2);
  bf16*  wovt  = (bf16*)alloc((size_t)256 * 1024 * 2);
  bf16*  wolt  = (bf16*)alloc((size_t)768 * 1024 * 2);
  bf16*  lb    = (bf16*)alloc((size_t)1024 * 768 * 2);
  bf16*  kh    = (bf16*)alloc((size_t)32 * 256 * 128 * 2);
  bf16*  vallT = (bf16*)alloc((size_t)32 * 128 * 256 * 2);
  float* olh   = (float*)alloc((size_t)1024 * 1024 * 4);      // atomic fallback only
  bf16*  olhb  = (bf16*)alloc((size_t)1024 * 1024 * 2);
  float* dsum  = (float*)alloc((size_t)2048 * 4);             // atomic fallback only
  // whole-input + per-b scratch (~134 MB)
  bf16*  vb      = (bf16*)alloc((size_t)4 * 16384 * 256 * 2); // 33.6 MB (all b, cast once)
  bf16*  qh_b    = (bf16*)alloc((size_t)8 * 16384 * 128 * 2); // 33.6 MB
  bf16*  valvT_b = (bf16*)alloc((size_t)8 * 128 * 16384 * 2); // 33.6 MB
  bf16*  ovh_b   = (bf16*)alloc((size_t)16384 * 1024 * 2);    // 33.6 MB
  const size_t off_base = off;                                 // ~152 MB

  const size_t slabh_b = (size_t)32 * 8 * 256 * 128 * 2;      // 16.78 MB
  const size_t csum_b  = (size_t)32 * 8 * 256 * 4;
  int tier;
  if (off_base + slabh_b + csum_b <= ws_size) tier = 0;        // ~169 MB <= proven 175
  else if (off_base <= ws_size) tier = 2;
  else {
    hipMemsetAsync(d_out, 0xFF, (size_t)out_size * 4, stream);
    return;
  }
  __half* slabh     = (__half*)(ws + off_base);
  float*  csum_slab = (float*)(ws + off_base + slabh_b);

  if (tier == 2) hipMemsetAsync(olh, 0, (size_t)1024 * 1024 * 4, stream);

  cast_weights<<<dim3(3072, 6), 256, 0, stream>>>(v_proj_w, wqt, vv_w, wvvt,
                                                  l_proj_w, wkt, vl_w, wvlt, ov_w, wovt, ol_w, wolt);
  cast_f32_bf16_v4<<<768, 256, 0, stream>>>(l, lb, 196608);
  cast_f32_bf16_v4<<<16384, 256, 0, stream>>>(v, vb, 4194304);   // all b, once
  gemm_kern<1><<<dim3(8, 8, 2), 256, 0, stream>>>(lb, wkt, wvlt, l_proj_b, vl_b,
                                                  kh, vallT, 0);

  for (int b = 0; b < 4; b++) {
    const bf16* kh_b    = kh    + (size_t)b * 8 * Sn * 128;
    const bf16* vallT_b = vallT + (size_t)b * 8 * 128 * Sn;
    const bf16* vb_b    = vb    + (size_t)b * 16384 * 256;
    gemm_kern<0><<<dim3(128, 8, 2), 256, 0, stream>>>(vb_b, wqt, wvvt, v_proj_b, vv_b,
                                                      qh_b, valvT_b, 0);
    if (tier == 0) {
      attn_fused<32, true><<<dim3(32, 8), 512, 0, stream>>>(qh_b, kh_b, vallT_b, valvT_b,
                                                            ovh_b, slabh, csum_slab);
    } else {
      hipMemsetAsync(dsum, 0, (size_t)2048 * 4, stream);
      attn_fused<32, false><<<dim3(32, 8), 512, 0, stream>>>(qh_b, kh_b, vallT_b, valvT_b,
                                                             ovh_b, olh + (size_t)b * 256 * 1024, dsum);
    }
    gemm_kern<2><<<dim3(128, 2, 1), 256, 0, stream>>>(ovh_b, wovt, wovt, ov_b, ov_b,
                                                      (float*)d_out + (size_t)b * 16384 * 256, nullptr, 0);
    if (tier == 0) reduce_olh<32><<<256, 256, 0, stream>>>(slabh, csum_slab, olhb + (size_t)b * 256 * 1024);
    else           norm_olh<<<256, 256, 0, stream>>>(olh + (size_t)b * 256 * 1024, dsum,
                                                     olhb + (size_t)b * 256 * 1024);
  }

  gemm_kern<3><<<dim3(8, 6, 1), 256, 0, stream>>>(olhb, wolt, wolt, ol_b, ol_b,
                                                  (float*)d_out + 16777216, nullptr, 0);
}

// Round 17
// 636.534 us; speedup vs baseline: 1.0181x; 1.0181x over previous
//
#include <hip/hip_runtime.h>
#include <hip/hip_bf16.h>
#include <hip/hip_fp16.h>

#define DI __device__ __forceinline__

typedef short bf16x8 __attribute__((ext_vector_type(8)));
typedef float f32x4 __attribute__((ext_vector_type(4)));
using bf16 = __hip_bfloat16;

typedef __attribute__((address_space(3))) void lds_void;
typedef const __attribute__((address_space(1))) void glob_void;

constexpr int Tn = 16384, Sn = 256, En = 1024;
constexpr float SCALEF = 0.08838834764831845f;   // 128^-0.5
constexpr float CLAMPF = 50000.0f;

DI f32x4 mfma16(bf16x8 a, bf16x8 b, f32x4 c) {
  return __builtin_amdgcn_mfma_f32_16x16x32_bf16(a, b, c, 0, 0, 0);
}
DI unsigned short f2bu(float x) { bf16 h = __float2bfloat16(x); return *(unsigned short*)&h; }
DI unsigned int pack2(float lo, float hi) { return (unsigned)f2bu(lo) | ((unsigned)f2bu(hi) << 16); }
DI bf16x8 ldg8(const bf16* p) { return *(const bf16x8*)p; }
DI float clampf(float v) { return fminf(fmaxf(v, -CLAMPF), CLAMPF); }
DI unsigned int packh2(float a, float b) {
  __half2 h = __floats2half2_rn(a, b);
  return *(unsigned int*)&h;
}
DI void gload16(const bf16* g, bf16* lds_base) {
  __builtin_amdgcn_global_load_lds((glob_void*)g, (lds_void*)lds_base, 16, 0, 0);
}

// ---------------- f32 -> bf16 bulk cast (vectorized x4) ----------------
__global__ void cast_f32_bf16_v4(const float* __restrict__ in, bf16* __restrict__ out, int n4) {
  int i = blockIdx.x * 256 + threadIdx.x;
  if (i >= n4) return;
  float4 f = reinterpret_cast<const float4*>(in)[i];
  unsigned long long u = (unsigned long long)pack2(f.x, f.y) |
                         ((unsigned long long)pack2(f.z, f.w) << 32);
  *reinterpret_cast<unsigned long long*>(out + (size_t)i * 4) = u;
}

// ---------------- weight transpose+cast W[K][N] -> Wt[N][K], y=0..5 ----------------
__global__ void cast_weights(const float* __restrict__ w0, bf16* __restrict__ o0,
                             const float* __restrict__ w1, bf16* __restrict__ o1,
                             const float* __restrict__ w2, bf16* __restrict__ o2,
                             const float* __restrict__ w3, bf16* __restrict__ o3,
                             const float* __restrict__ w4, bf16* __restrict__ o4,
                             const float* __restrict__ w5, bf16* __restrict__ o5) {
  int id = blockIdx.x * 256 + threadIdx.x;
  switch (blockIdx.y) {
    case 0: if (id < 256*1024) { int k = id >> 10, n = id & 1023; o0[n*256 + k] = __float2bfloat16(w0[id]); } break;
    case 1: if (id < 256*1024) { int k = id >> 10, n = id & 1023; o1[n*256 + k] = __float2bfloat16(w1[id]); } break;
    case 2: if (id < 768*1024) { int k = id >> 10, n = id & 1023; o2[n*768 + k] = __float2bfloat16(w2[id]); } break;
    case 3: if (id < 768*1024) { int k = id >> 10, n = id & 1023; o3[n*768 + k] = __float2bfloat16(w3[id]); } break;
    case 4: if (id < 1024*256) { int k = id >> 8,  n = id & 255;  o4[n*1024 + k] = __float2bfloat16(w4[id]); } break;
    case 5: if (id < 1024*768) { int k = id / 768, n = id % 768;  o5[n*1024 + k] = __float2bfloat16(w5[id]); } break;
  }
}

// ---------------- generic 128x128 MFMA GEMM (R12-proven) ----------------
template<int MODE>
__global__ __launch_bounds__(256) void gemm_kern(
    const bf16* __restrict__ A, const bf16* __restrict__ Bw0, const bf16* __restrict__ Bw1,
    const float* __restrict__ bias0, const float* __restrict__ bias1,
    void* __restrict__ out0, void* __restrict__ out1, int zbase)
{
  constexpr int K = (MODE == 0) ? 256 : (MODE == 1) ? 768 : 1024;
  const int z = blockIdx.z + zbase;
  const bf16* Bw = z ? Bw1 : Bw0;
  const float* bias = z ? bias1 : bias0;
  const int m0 = blockIdx.x * 128, n0 = blockIdx.y * 128;
  const int tid = threadIdx.x, lane = tid & 63;
  const int w = tid >> 6, wm = w >> 1, wn = w & 1;
  const int l15 = lane & 15, l4 = lane >> 4;

  __shared__ bf16 smem[128 * 136];
  bf16* As = smem;
  bf16* Bs = smem + 128 * 64;

  const int lr = lane >> 3, lp = lane & 7;

  f32x4 acc[4][4];
  #pragma unroll
  for (int a = 0; a < 4; a++)
    #pragma unroll
    for (int c = 0; c < 4; c++) acc[a][c] = f32x4{0.f, 0.f, 0.f, 0.f};

  for (int k0 = 0; k0 < K; k0 += 64) {
    __syncthreads();
    #pragma unroll
    for (int it = 0; it < 4; it++) {
      const int row = it * 32 + w * 8 + lr;
      const int gc = lp ^ (row & 7);
      gload16(Bw + (size_t)(n0 + row) * K + k0 + gc * 8, Bs + (it * 32 + w * 8) * 64);
      gload16(A  + (size_t)(m0 + row) * K + k0 + gc * 8, As + (it * 32 + w * 8) * 64);
    }
    __syncthreads();
    #pragma unroll
    for (int ks = 0; ks < 2; ks++) {
      bf16x8 af[4], bfr[4];
      #pragma unroll
      for (int mf = 0; mf < 4; mf++) {
        int r = wm * 64 + mf * 16 + l15;
        af[mf] = *(const bf16x8*)(As + r * 64 + (((ks * 4 + l4) ^ (r & 7)) * 8));
      }
      #pragma unroll
      for (int nf = 0; nf < 4; nf++) {
        int r = wn * 64 + nf * 16 + l15;
        bfr[nf] = *(const bf16x8*)(Bs + r * 64 + (((ks * 4 + l4) ^ (r & 7)) * 8));
      }
      #pragma unroll
      for (int mf = 0; mf < 4; mf++)
        #pragma unroll
        for (int nf = 0; nf < 4; nf++)
          acc[mf][nf] = mfma16(af[mf], bfr[nf], acc[mf][nf]);
    }
  }
  __syncthreads();

  if constexpr (MODE <= 1) {
    #pragma unroll
    for (int nf = 0; nf < 4; nf++) {
      int nl = wn * 64 + nf * 16 + l15;
      float bv = bias[n0 + nl];
      #pragma unroll
      for (int mf = 0; mf < 4; mf++) {
        int ml = wm * 64 + mf * 16 + l4 * 4;
        #pragma unroll
        for (int i = 0; i < 4; i++) {
          float vv = acc[mf][nf][i] + bv;
          if (MODE == 0 && z == 0) vv *= SCALEF;
          smem[(ml + i) * 136 + nl] = __float2bfloat16(vv);
        }
      }
    }
    __syncthreads();
    constexpr int TT = (MODE == 0) ? Tn : Sn;
    const int h = n0 >> 7;
    const int r2 = tid >> 1, c0 = (tid & 1) * 64;
    if (z == 0) {
      int m = m0 + r2;
      int bq = (MODE == 0) ? 0 : (m >> 8);
      int t  = m & (TT - 1);
      bf16* out = (bf16*)out0;
      size_t base = ((size_t)(bq * 8 + h) * TT + t) * 128 + c0;
      #pragma unroll
      for (int j = 0; j < 32; j++) {
        unsigned int u = *(const unsigned int*)(smem + r2 * 136 + c0 + 2 * j);
        *(unsigned int*)(out + base + 2 * j) = u;
      }
    } else {
      int bq = (MODE == 0) ? 0 : (m0 >> 8);
      int t0 = m0 & (TT - 1);
      bf16* out = (bf16*)out1;
      size_t base = ((size_t)(bq * 8 + h) * 128 + r2) * TT + t0 + c0;
      #pragma unroll
      for (int j = 0; j < 32; j++) {
        unsigned short u0 = *(const unsigned short*)(smem + (c0 + 2 * j)     * 136 + r2);
        unsigned short u1 = *(const unsigned short*)(smem + (c0 + 2 * j + 1) * 136 + r2);
        *(unsigned int*)(out + base + 2 * j) = (unsigned)u0 | ((unsigned)u1 << 16);
      }
    }
  } else {
    constexpr int NOUT = (MODE == 2) ? 256 : 768;
    float* out = (float*)out0;
    #pragma unroll
    for (int nf = 0; nf < 4; nf++) {
      int n = n0 + wn * 64 + nf * 16 + l15;
      float bv = bias[n];
      #pragma unroll
      for (int mf = 0; mf < 4; mf++) {
        size_t mbase = (size_t)(m0 + wm * 64 + mf * 16 + l4 * 4) * NOUT + n;
        #pragma unroll
        for (int i = 0; i < 4; i++)
          out[mbase + (size_t)i * NOUT] = acc[mf][nf][i] + bv;
      }
    }
  }
}

// ---------------- FUSED attention v2.5: R15 body + isolated T5 setprio ---------------
// Byte-identical structure to the 78.8us R15 kernel; only addition is
// s_setprio(1)/(0) around the three MFMA clusters (T5, m191: +4-7% on attn with
// wave role diversity — here waves diverge between barriers).
template<int NCH, bool SLAB>
__global__ __launch_bounds__(512, 2) void attn_fused(
    const bf16* __restrict__ qh,      // [8][Tn][128]
    const bf16* __restrict__ kh,      // [8][Sn][128]
    const bf16* __restrict__ vallT,   // [8][128][Sn]
    const bf16* __restrict__ valvT,   // [8][128][Tn]
    bf16* __restrict__ ovh,           // [Tn][En]
    void* __restrict__ col_dst,       // SLAB ? __half slab : float olh (pre-zeroed)
    float* __restrict__ dsum_dst)     // SLAB ? csum_slab : dsum (pre-zeroed, atomic)
{
  constexpr int SPAN = Tn / NCH;      // 512
  constexpr int TILES = SPAN / 64;    // 8
  const int ch = blockIdx.x, h = blockIdx.y;
  const int tid = threadIdx.x, lane = tid & 63, w = tid >> 6;   // 8 waves
  const int l15 = lane & 15, l4 = lane >> 4;
  const int sw = w * 32;
  const int e7 = l15 & 7;

  __shared__ bf16 Qb[2][64 * 128];    // 32 KB
  __shared__ bf16 Vb[2][128 * 64];    // 32 KB
  __shared__ bf16 Enat[64 * 264];     // 33.8 KB
  __shared__ bf16 Etr[8][32 * 72];    // 36.9 KB
  __shared__ float red[8][64];        // 2 KB   (total ~135 KB -> 1 blk/CU)

  const bf16* qp  = qh    + (size_t)h * Tn * 128;
  const bf16* kp  = kh    + (size_t)h * Sn * 128;
  const bf16* vlp = vallT + (size_t)h * 128 * Sn;
  const bf16* vvp = valvT + (size_t)h * 128 * Tn;
  const int tb0 = ch * SPAN;

  bf16x8 bkr[4][2];
  #pragma unroll
  for (int ks = 0; ks < 4; ks++)
    #pragma unroll
    for (int si = 0; si < 2; si++)
      bkr[ks][si] = ldg8(kp + (size_t)(sw + si * 16 + l15) * 128 + ks * 32 + l4 * 8);
  bf16x8 bvr[8];
  #pragma unroll
  for (int ks2 = 0; ks2 < 8; ks2++)
    bvr[ks2] = ldg8(vlp + (size_t)(w * 16 + l15) * Sn + ks2 * 32 + l4 * 8);

  const int q_r0 = tid >> 4, q_c = tid & 15;          // Q: 64r x 16c
  const int q_r1 = q_r0 + 32;
  const int v_r0 = tid >> 3, v_c = tid & 7;           // V: 128r x 8c
  const int v_r1 = v_r0 + 64;

  {
    uint4 q0 = *(const uint4*)(qp + (size_t)(tb0 + q_r0) * 128 + q_c * 8);
    uint4 q1 = *(const uint4*)(qp + (size_t)(tb0 + q_r1) * 128 + q_c * 8);
    uint4 v0 = *(const uint4*)(vvp + (size_t)v_r0 * Tn + tb0 + v_c * 8);
    uint4 v1 = *(const uint4*)(vvp + (size_t)v_r1 * Tn + tb0 + v_c * 8);
    *(uint4*)(&Qb[0][q_r0 * 128 + ((q_c ^ (q_r0 & 7)) * 8)]) = q0;
    *(uint4*)(&Qb[0][q_r1 * 128 + ((q_c ^ (q_r1 & 7)) * 8)]) = q1;
    *(uint4*)(&Vb[0][v_r0 * 64  + ((v_c ^ (v_r0 & 7)) * 8)]) = v0;
    *(uint4*)(&Vb[0][v_r1 * 64  + ((v_c ^ (v_r1 & 7)) * 8)]) = v1;
  }
  __syncthreads();

  f32x4 oc[8][2];
  #pragma unroll
  for (int a = 0; a < 8; a++)
    #pragma unroll
    for (int c = 0; c < 2; c++) oc[a][c] = f32x4{0.f, 0.f, 0.f, 0.f};
  float csum[2] = {0.f, 0.f};

  int cur = 0;
  for (int tt = 0; tt < TILES; tt++) {
    const int tb = tb0 + tt * 64;
    const bool hn = (tt + 1 < TILES);
    uint4 pfq0, pfq1, pfv0, pfv1;
    if (hn) {
      const int tbn = tb + 64;
      pfq0 = *(const uint4*)(qp + (size_t)(tbn + q_r0) * 128 + q_c * 8);
      pfq1 = *(const uint4*)(qp + (size_t)(tbn + q_r1) * 128 + q_c * 8);
      pfv0 = *(const uint4*)(vvp + (size_t)v_r0 * Tn + tbn + v_c * 8);
      pfv1 = *(const uint4*)(vvp + (size_t)v_r1 * Tn + tbn + v_c * 8);
    }
    // ---- QK^T from Qb[cur] ----
    f32x4 sacc[4][2];
    #pragma unroll
    for (int a = 0; a < 4; a++)
      #pragma unroll
      for (int c = 0; c < 2; c++) sacc[a][c] = f32x4{0.f, 0.f, 0.f, 0.f};
    __builtin_amdgcn_s_setprio(1);
    #pragma unroll
    for (int ks = 0; ks < 4; ks++) {
      const int x = (ks * 4 + l4) ^ e7;
      bf16x8 aq[4];
      #pragma unroll
      for (int ti = 0; ti < 4; ti++)
        aq[ti] = *(const bf16x8*)(&Qb[cur][(ti * 16 + l15) * 128 + x * 8]);
      #pragma unroll
      for (int ti = 0; ti < 4; ti++)
        #pragma unroll
        for (int si = 0; si < 2; si++)
          sacc[ti][si] = mfma16(aq[ti], bkr[ks][si], sacc[ti][si]);
    }
    __builtin_amdgcn_s_setprio(0);
    // ---- E = exp(clamp(S)) -> Enat + Etr; col sums; row partials ----
    float rp[4][4];
    #pragma unroll
    for (int ti = 0; ti < 4; ti++)
      #pragma unroll
      for (int i = 0; i < 4; i++) rp[ti][i] = 0.f;
    #pragma unroll
    for (int ti = 0; ti < 4; ti++)
      #pragma unroll
      for (int si = 0; si < 2; si++) {
        float e0 = __expf(clampf(sacc[ti][si][0]));
        float e1 = __expf(clampf(sacc[ti][si][1]));
        float e2 = __expf(clampf(sacc[ti][si][2]));
        float e3 = __expf(clampf(sacc[ti][si][3]));
        csum[si] += (e0 + e1) + (e2 + e3);
        rp[ti][0] += e0; rp[ti][1] += e1; rp[ti][2] += e2; rp[ti][3] += e3;
        unsigned long long u = (unsigned long long)pack2(e0, e1) |
                               ((unsigned long long)pack2(e2, e3) << 32);
        *(unsigned long long*)(&Etr[w][(si * 16 + l15) * 72 + ti * 16 + l4 * 4]) = u;
        const int s = sw + si * 16 + l15;
        const int t0 = ti * 16 + l4 * 4;
        Enat[(t0 + 0) * 264 + s] = __float2bfloat16(e0);
        Enat[(t0 + 1) * 264 + s] = __float2bfloat16(e1);
        Enat[(t0 + 2) * 264 + s] = __float2bfloat16(e2);
        Enat[(t0 + 3) * 264 + s] = __float2bfloat16(e3);
      }
    #pragma unroll
    for (int ti = 0; ti < 4; ti++)
      #pragma unroll
      for (int i = 0; i < 4; i++) {
        float r = rp[ti][i];
        #pragma unroll
        for (int off = 1; off < 16; off <<= 1) r += __shfl_xor(r, off);
        if (l15 == 0) red[w][ti * 16 + l4 * 4 + i] = r;
      }
    __syncthreads();
    float rsm[4][4];
    #pragma unroll
    for (int ti = 0; ti < 4; ti++)
      #pragma unroll
      for (int i = 0; i < 4; i++) {
        const int tl = ti * 16 + l4 * 4 + i;
        float s = red[0][tl] + red[1][tl] + red[2][tl] + red[3][tl] +
                  red[4][tl] + red[5][tl] + red[6][tl] + red[7][tl];
        rsm[ti][i] = 1.0f / s;
      }
    // ---- row-PV from Enat + hoisted bvr; in-kernel 1/rowsum scaling ----
    f32x4 orr[4];
    #pragma unroll
    for (int a = 0; a < 4; a++) orr[a] = f32x4{0.f, 0.f, 0.f, 0.f};
    __builtin_amdgcn_s_setprio(1);
    #pragma unroll
    for (int ks2 = 0; ks2 < 8; ks2++) {
      const int soff = ks2 * 32 + l4 * 8;
      #pragma unroll
      for (int ti = 0; ti < 4; ti++) {
        bf16x8 ap = *(const bf16x8*)(Enat + (ti * 16 + l15) * 264 + soff);
        orr[ti] = mfma16(ap, bvr[ks2], orr[ti]);
      }
    }
    __builtin_amdgcn_s_setprio(0);
    #pragma unroll
    for (int ti = 0; ti < 4; ti++) {
      size_t base = (size_t)(tb + ti * 16 + l4 * 4) * En + h * 128 + w * 16 + l15;
      #pragma unroll
      for (int i = 0; i < 4; i++)
        ovh[base + (size_t)i * En] = __float2bfloat16(orr[ti][i] * rsm[ti][i]);
    }
    // ---- col-PV from Etr (wave-private) + Vb[cur] ----
    __builtin_amdgcn_s_setprio(1);
    #pragma unroll
    for (int kst = 0; kst < 2; kst++) {
      bf16x8 bp[2];
      #pragma unroll
      for (int si = 0; si < 2; si++)
        bp[si] = *(const bf16x8*)(&Etr[w][(si * 16 + l15) * 72 + kst * 32 + l4 * 8]);
      const int x = (kst * 4 + l4) ^ e7;
      #pragma unroll
      for (int mf = 0; mf < 8; mf++) {
        bf16x8 av = *(const bf16x8*)(&Vb[cur][(mf * 16 + l15) * 64 + x * 8]);
        #pragma unroll
        for (int si = 0; si < 2; si++)
          oc[mf][si] = mfma16(av, bp[si], oc[mf][si]);
      }
    }
    __builtin_amdgcn_s_setprio(0);
    if (hn) {
      *(uint4*)(&Qb[cur ^ 1][q_r0 * 128 + ((q_c ^ (q_r0 & 7)) * 8)]) = pfq0;
      *(uint4*)(&Qb[cur ^ 1][q_r1 * 128 + ((q_c ^ (q_r1 & 7)) * 8)]) = pfq1;
      *(uint4*)(&Vb[cur ^ 1][v_r0 * 64  + ((v_c ^ (v_r0 & 7)) * 8)]) = pfv0;
      *(uint4*)(&Vb[cur ^ 1][v_r1 * 64  + ((v_c ^ (v_r1 & 7)) * 8)]) = pfv1;
    }
    __syncthreads();
    cur ^= 1;
  }
  // ---- epilogue: col denominator + numerator ----
  #pragma unroll
  for (int si = 0; si < 2; si++) {
    float c = csum[si];
    c += __shfl_xor(c, 16);
    c += __shfl_xor(c, 32);
    if (l4 == 0) {
      if constexpr (SLAB) dsum_dst[((size_t)(ch * 8 + h)) * 256 + sw + si * 16 + l15] = c;
      else atomicAdd(&dsum_dst[h * 256 + sw + si * 16 + l15], c);
    }
  }
  if constexpr (SLAB) {
    __half* slab = (__half*)col_dst + ((size_t)(ch * 8 + h) * 256) * 128;
    #pragma unroll
    for (int mf = 0; mf < 8; mf++)
      #pragma unroll
      for (int si = 0; si < 2; si++) {
        const int s = sw + si * 16 + l15;
        const int d = mf * 16 + l4 * 4;
        uint2 u;
        u.x = packh2(oc[mf][si][0], oc[mf][si][1]);
        u.y = packh2(oc[mf][si][2], oc[mf][si][3]);
        *(uint2*)(slab + (size_t)s * 128 + d) = u;
      }
  } else {
    float* olh = (float*)col_dst;
    #pragma unroll
    for (int mf = 0; mf < 8; mf++)
      #pragma unroll
      for (int si = 0; si < 2; si++) {
        const int s = sw + si * 16 + l15;
        const int d = mf * 16 + l4 * 4;
        float* dst = olh + (size_t)s * 1024 + h * 128 + d;
        #pragma unroll
        for (int i = 0; i < 4; i++) atomicAdd(dst + i, oc[mf][si][i]);
      }
  }
}

// ---------------- slab reduce (fp16 numerator + f32 denominator) -> bf16 olhb --------
template<int NCH>
__global__ __launch_bounds__(256) void reduce_olh(
    const __half* __restrict__ slab, const float* __restrict__ csum_slab, bf16* __restrict__ olhb)
{
  int id = blockIdx.x * 256 + threadIdx.x;
  int s = id >> 8, hd4 = id & 255, h = hd4 >> 5, d4 = hd4 & 31;
  float a0 = 0.f, a1 = 0.f, a2 = 0.f, a3 = 0.f, dsv = 0.f;
  #pragma unroll 4
  for (int ch = 0; ch < NCH; ch++) {
    uint2 u = *(const uint2*)(slab + ((size_t)(ch * 8 + h) * 256 + s) * 128 + d4 * 4);
    __half2 x = *(__half2*)&u.x, y = *(__half2*)&u.y;
    a0 += __low2float(x); a1 += __high2float(x);
    a2 += __low2float(y); a3 += __high2float(y);
    dsv += csum_slab[((size_t)(ch * 8 + h)) * 256 + s];
  }
  float inv = 1.0f / dsv;
  unsigned long long u = (unsigned long long)pack2(a0 * inv, a1 * inv) |
                         ((unsigned long long)pack2(a2 * inv, a3 * inv) << 32);
  *reinterpret_cast<unsigned long long*>(olhb + (size_t)s * 1024 + h * 128 + d4 * 4) = u;
}

// ---------------- fallback normalize olh -> bf16 (per-b) ----------------
__global__ __launch_bounds__(256) void norm_olh(
    const float* __restrict__ olh, const float* __restrict__ dsum, bf16* __restrict__ olhb)
{
  int i = blockIdx.x * 256 + threadIdx.x;
  int s = i >> 8, c4 = i & 255;
  float inv = 1.0f / dsum[(c4 >> 5) * 256 + s];
  float4 x = reinterpret_cast<const float4*>(olh + (size_t)s * 1024)[c4];
  unsigned long long u = (unsigned long long)pack2(x.x * inv, x.y * inv) |
                         ((unsigned long long)pack2(x.z * inv, x.w * inv) << 32);
  *reinterpret_cast<unsigned long long*>(olhb + (size_t)s * 1024 + c4 * 4) = u;
}

// ---------------- launch ----------------
extern "C" void kernel_launch(void* const* d_in, const int* in_sizes, int n_in,
                              void* d_out, int out_size, void* d_ws, size_t ws_size,
                              hipStream_t stream)
{
  (void)in_sizes; (void)n_in;
  const float* v        = (const float*)d_in[0];
  const float* l        = (const float*)d_in[1];
  const float* v_proj_w = (const float*)d_in[2];
  const float* v_proj_b = (const float*)d_in[3];
  const float* l_proj_w = (const float*)d_in[4];
  const float* l_proj_b = (const float*)d_in[5];
  const float* vv_w     = (const float*)d_in[6];
  const float* vv_b     = (const float*)d_in[7];
  const float* vl_w     = (const float*)d_in[8];
  const float* vl_b     = (const float*)d_in[9];
  const float* ov_w     = (const float*)d_in[10];
  const float* ov_b     = (const float*)d_in[11];
  const float* ol_w     = (const float*)d_in[12];
  const float* ol_b     = (const float*)d_in[13];

  char* ws = (char*)d_ws;
  size_t off = 0;
  auto alloc = [&](size_t bytes) -> char* {
    char* p = ws + off;
    off += (bytes + 255) & ~(size_t)255;
    return p;
  };

  // persistent (~18 MB)
  bf16*  wqt   = (bf16*)alloc((size_t)1024 * 256 * 2);
  bf16*  wvvt  = (bf16*)alloc((size_t)1024 * 256 * 2);
  bf16*  wkt   = (bf16*)alloc((size_t)1024 * 768 * 2);
  bf16*  wvlt  = (bf16*)alloc((size_t)1024 * 768 * 2);
  bf16*  wovt  = (bf16*)alloc((size_t)256 * 1024 * 2);
  bf16*  wolt  = (bf16*)alloc((size_t)768 * 1024 * 2);
  bf16*  lb    = (bf16*)alloc((size_t)1024 * 768 * 2);
  bf16*  kh    = (bf16*)alloc((size_t)32 * 256 * 128 * 2);
  bf16*  vallT = (bf16*)alloc((size_t)32 * 128 * 256 * 2);
  float* olh   = (float*)alloc((size_t)1024 * 1024 * 4);      // atomic fallback only
  bf16*  olhb  = (bf16*)alloc((size_t)1024 * 1024 * 2);
  float* dsum  = (float*)alloc((size_t)2048 * 4);             // atomic fallback only
  // whole-input + per-b scratch (~134 MB)
  bf16*  vb      = (bf16*)alloc((size_t)4 * 16384 * 256 * 2); // 33.6 MB (all b, cast once)
  bf16*  qh_b    = (bf16*)alloc((size_t)8 * 16384 * 128 * 2); // 33.6 MB
  bf16*  valvT_b = (bf16*)alloc((size_t)8 * 128 * 16384 * 2); // 33.6 MB
  bf16*  ovh_b   = (bf16*)alloc((size_t)16384 * 1024 * 2);    // 33.6 MB
  const size_t off_base = off;                                 // ~152 MB

  const size_t slabh_b = (size_t)32 * 8 * 256 * 128 * 2;      // 16.78 MB
  const size_t csum_b  = (size_t)32 * 8 * 256 * 4;
  int tier;
  if (off_base + slabh_b + csum_b <= ws_size) tier = 0;        // ~169 MB <= proven 175
  else if (off_base <= ws_size) tier = 2;
  else {
    hipMemsetAsync(d_out, 0xFF, (size_t)out_size * 4, stream);
    return;
  }
  __half* slabh     = (__half*)(ws + off_base);
  float*  csum_slab = (float*)(ws + off_base + slabh_b);

  if (tier == 2) hipMemsetAsync(olh, 0, (size_t)1024 * 1024 * 4, stream);

  cast_weights<<<dim3(3072, 6), 256, 0, stream>>>(v_proj_w, wqt, vv_w, wvvt,
                                                  l_proj_w, wkt, vl_w, wvlt, ov_w, wovt, ol_w, wolt);
  cast_f32_bf16_v4<<<768, 256, 0, stream>>>(l, lb, 196608);
  cast_f32_bf16_v4<<<16384, 256, 0, stream>>>(v, vb, 4194304);   // all b, once
  gemm_kern<1><<<dim3(8, 8, 2), 256, 0, stream>>>(lb, wkt, wvlt, l_proj_b, vl_b,
                                                  kh, vallT, 0);

  for (int b = 0; b < 4; b++) {
    const bf16* kh_b    = kh    + (size_t)b * 8 * Sn * 128;
    const bf16* vallT_b = vallT + (size_t)b * 8 * 128 * Sn;
    const bf16* vb_b    = vb    + (size_t)b * 16384 * 256;
    gemm_kern<0><<<dim3(128, 8, 2), 256, 0, stream>>>(vb_b, wqt, wvvt, v_proj_b, vv_b,
                                                      qh_b, valvT_b, 0);
    if (tier == 0) {
      attn_fused<32, true><<<dim3(32, 8), 512, 0, stream>>>(qh_b, kh_b, vallT_b, valvT_b,
                                                            ovh_b, slabh, csum_slab);
    } else {
      hipMemsetAsync(dsum, 0, (size_t)2048 * 4, stream);
      attn_fused<32, false><<<dim3(32, 8), 512, 0, stream>>>(qh_b, kh_b, vallT_b, valvT_b,
                                                             ovh_b, olh + (size_t)b * 256 * 1024, dsum);
    }
    gemm_kern<2><<<dim3(128, 2, 1), 256, 0, stream>>>(ovh_b, wovt, wovt, ov_b, ov_b,
                                                      (float*)d_out + (size_t)b * 16384 * 256, nullptr, 0);
    if (tier == 0) reduce_olh<32><<<256, 256, 0, stream>>>(slabh, csum_slab, olhb + (size_t)b * 256 * 1024);
    else           norm_olh<<<256, 256, 0, stream>>>(olh + (size_t)b * 256 * 1024, dsum,
                                                     olhb + (size_t)b * 256 * 1024);
  }

  gemm_kern<3><<<dim3(8, 6, 1), 256, 0, stream>>>(olhb, wolt, wolt, ol_b, ol_b,
                                                  (float*)d_out + 16777216, nullptr, 0);
}